// Round 12
// baseline (370.796 us; speedup 1.0000x reference)
//
#include <hip/hip_runtime.h>
#include <hip/hip_bf16.h>

// GCN, CSR-gather, bf16 T-tables, SPLIT aggregate/transform:
//   T = bf16(f(X)*dinv);  S[d] = sum_{s in N(d)} T[s] + T[d]   (agg_s, depth-8 gather)
//   Y[d] = dinv[d]*(S[d]@W) + b  in-place via scalar-operand matvec (trans64)
// agg_s: one node/wave, 8 slots x 8 bf16/lane; 64 csr idx in ONE load; 8 row-loads
// in flight before accumulate. No LDS, no W, no stats -> minimal VGPR/latency.

__device__ __forceinline__ unsigned f2bf(float f) {   // round-to-nearest-even
    unsigned u = __float_as_uint(f);
    return (u + 0x7FFFu + ((u >> 16) & 1u)) >> 16;
}
__device__ __forceinline__ float bflo(unsigned w) { return __uint_as_float(w << 16); }
__device__ __forceinline__ float bfhi(unsigned w) { return __uint_as_float(w & 0xFFFF0000u); }

// ---- degree count ----
__global__ void deg_count(const int* __restrict__ dst, int* __restrict__ degi, int E) {
    int tid = blockIdx.x * blockDim.x + threadIdx.x;
    int stride = gridDim.x * blockDim.x;
    for (int e = tid; e < E; e += stride) atomicAdd(&degi[dst[e]], 1);
}

__global__ void scan_part(const int* __restrict__ degi, int* __restrict__ part, int n) {
    __shared__ int ls[256];
    int i = blockIdx.x * 256 + threadIdx.x;
    ls[threadIdx.x] = (i < n) ? degi[i] : 0;
    __syncthreads();
    for (int o = 128; o > 0; o >>= 1) {
        if (threadIdx.x < o) ls[threadIdx.x] += ls[threadIdx.x + o];
        __syncthreads();
    }
    if (threadIdx.x == 0) part[blockIdx.x] = ls[0];
}

__global__ void scan_root(int* __restrict__ part, int nblk) {   // nblk <= 256
    __shared__ int ls[256];
    int t = threadIdx.x;
    int v = (t < nblk) ? part[t] : 0;
    ls[t] = v;
    __syncthreads();
    for (int o = 1; o < 256; o <<= 1) {
        int u = (t >= o) ? ls[t - o] : 0;
        __syncthreads();
        ls[t] += u;
        __syncthreads();
    }
    if (t < nblk) part[t] = ls[t] - v;   // exclusive
}

__global__ void scan_write(const int* __restrict__ degi, const int* __restrict__ part,
                           int* __restrict__ off, int* __restrict__ cur,
                           float* __restrict__ dinv, int n) {
    __shared__ int ls[256];
    int t = threadIdx.x, i = blockIdx.x * 256 + t;
    int d = (i < n) ? degi[i] : 0;
    ls[t] = d;
    __syncthreads();
    for (int o = 1; o < 256; o <<= 1) {
        int u = (t >= o) ? ls[t - o] : 0;
        __syncthreads();
        ls[t] += u;
        __syncthreads();
    }
    if (i < n) {
        int o0 = part[blockIdx.x] + ls[t] - d;
        off[i] = o0;
        cur[i] = o0;
        dinv[i] = rsqrtf((float)d + 1.0f);   // +1 self loop
        if (i == n - 1) off[n] = o0 + d;
    }
}

// ---- windowed CSR fill: block-group (blockIdx&7) owns one n/8 dst-window ----
__global__ void csr_fill_x(const int* __restrict__ src, const int* __restrict__ dst,
                           int* __restrict__ cur, int* __restrict__ csr, int E, int n) {
    int w = blockIdx.x & 7;
    int lo = (int)(((long long)n * w) >> 3);
    int hi = (int)(((long long)n * (w + 1)) >> 3);
    int tid = (blockIdx.x >> 3) * blockDim.x + threadIdx.x;
    int stride = (gridDim.x >> 3) * blockDim.x;
    for (int e = tid; e < E; e += stride) {
        int d = dst[e];
        if (d >= lo && d < hi) {
            int p = atomicAdd(&cur[d], 1);
            csr[p] = src[e];
        }
    }
}

// ---- T1 = bf16(x * dinv) ----
__global__ void prescale(const float* __restrict__ x, const float* __restrict__ dinv,
                         unsigned* __restrict__ T, int n) {
    int tid = blockIdx.x * blockDim.x + threadIdx.x;
    int stride = gridDim.x * blockDim.x;
    int total = n * 32;   // u32 count (2 features each)
    const float2* x2 = (const float2*)x;
    for (int i = tid; i < total; i += stride) {
        float2 v = x2[i];
        float dv = dinv[i >> 5];
        T[i] = f2bf(v.x * dv) | (f2bf(v.y * dv) << 16);
    }
}

// ---- T2 = bf16(relu(BN(y)) * dinv) ----
__global__ void bnrelu_scale(const float* __restrict__ Y, const double* __restrict__ stats,
                             const float* __restrict__ g, const float* __restrict__ bt,
                             const float* __restrict__ dinv, unsigned* __restrict__ T, int n) {
    int jj = threadIdx.x & 31;            // u32 index within row
    int f0 = jj * 2, f1 = jj * 2 + 1;
    double m0 = stats[f0] / n, m1 = stats[f1] / n;
    double v0 = stats[64 + f0] / n - m0 * m0, v1 = stats[64 + f1] / n - m1 * m1;
    float sc0 = (float)(1.0 / sqrt(v0 + 1e-5)) * g[f0];
    float sc1 = (float)(1.0 / sqrt(v1 + 1e-5)) * g[f1];
    float sh0 = bt[f0] - (float)m0 * sc0;
    float sh1 = bt[f1] - (float)m1 * sc1;
    const float2* Y2 = (const float2*)Y;
    int tid = blockIdx.x * blockDim.x + threadIdx.x;
    int stride = gridDim.x * blockDim.x;   // multiple of 32
    for (int i = tid; i < n * 32; i += stride) {
        float2 y = Y2[i];
        float dv = dinv[i >> 5];
        float a = fmaxf(y.x * sc0 + sh0, 0.f) * dv;
        float b = fmaxf(y.y * sc1 + sh1, 0.f) * dv;
        T[i] = f2bf(a) | (f2bf(b) << 16);
    }
}

// ---- aggregate only: S[i] = sum of T rows (self + neighbors), depth-8 gather ----
__global__ __launch_bounds__(256) void agg_s(
        const uint4* __restrict__ Tb, const int* __restrict__ csr,
        const int* __restrict__ off, float* __restrict__ S, int n) {
    int lane = threadIdx.x & 63;
    int slot = lane >> 3;      // 8 edge slots
    int fl   = lane & 7;       // features 8*fl..8*fl+7 (one uint4 = 8 bf16)

    int wave  = (blockIdx.x * blockDim.x + threadIdx.x) >> 6;
    int nwave = (gridDim.x * blockDim.x) >> 6;

    for (int i = wave; i < n; i += nwave) {
        int beg = off[i], end = off[i + 1];
        int cnt = end - beg;
        // one instruction loads up to 64 edge indices
        int idx = (lane < cnt) ? csr[beg + lane] : 0;

        float4 al = {0,0,0,0}, ah = {0,0,0,0};
        if (slot == 0) {                       // self term in slot 0 only
            uint4 r = Tb[(size_t)i * 8 + fl];
            al.x = bflo(r.x); al.y = bfhi(r.x);
            al.z = bflo(r.y); al.w = bfhi(r.y);
            ah.x = bflo(r.z); ah.y = bfhi(r.z);
            ah.z = bflo(r.w); ah.w = bfhi(r.w);
        }

        // this slot's 8 edges: ordinals slot*8+t; issue ALL loads, then accumulate
        int base = slot * 8;
        uint4 r[8];
        bool v[8];
        #pragma unroll
        for (int t = 0; t < 8; ++t) {
            int row = __shfl(idx, base + t, 64);
            v[t] = (base + t) < cnt;
            r[t] = Tb[(size_t)(v[t] ? row : 0) * 8 + fl];
        }
        #pragma unroll
        for (int t = 0; t < 8; ++t) {
            if (v[t]) {
                al.x += bflo(r[t].x); al.y += bfhi(r[t].x);
                al.z += bflo(r[t].y); al.w += bfhi(r[t].y);
                ah.x += bflo(r[t].z); ah.y += bfhi(r[t].z);
                ah.z += bflo(r[t].w); ah.w += bfhi(r[t].w);
            }
        }
        // rare tail (deg > 64)
        for (int c = beg + 64 + slot; c < end; c += 8) {
            int sr = csr[c];
            uint4 rr = Tb[(size_t)sr * 8 + fl];
            al.x += bflo(rr.x); al.y += bfhi(rr.x);
            al.z += bflo(rr.y); al.w += bfhi(rr.y);
            ah.x += bflo(rr.z); ah.y += bfhi(rr.z);
            ah.z += bflo(rr.w); ah.w += bfhi(rr.w);
        }

        // reduce across the 8 slots (lane bits 3,4,5)
        #pragma unroll
        for (int m = 8; m <= 32; m <<= 1) {
            al.x += __shfl_xor(al.x, m, 64); al.y += __shfl_xor(al.y, m, 64);
            al.z += __shfl_xor(al.z, m, 64); al.w += __shfl_xor(al.w, m, 64);
            ah.x += __shfl_xor(ah.x, m, 64); ah.y += __shfl_xor(ah.y, m, 64);
            ah.z += __shfl_xor(ah.z, m, 64); ah.w += __shfl_xor(ah.w, m, 64);
        }

        // lane stores feature 8*fl + slot  (component 'slot' of its chunk)
        float out = (slot == 0) ? al.x : (slot == 1) ? al.y : (slot == 2) ? al.z
                  : (slot == 3) ? al.w : (slot == 4) ? ah.x : (slot == 5) ? ah.y
                  : (slot == 6) ? ah.z : ah.w;
        S[(size_t)i * 64 + 8 * fl + slot] = out;
    }
}

// ---- in-place transform: Y = dinv*(S@W) + b, stats fused; W column in VGPRs ----
__global__ __launch_bounds__(256) void trans64(
        float* __restrict__ SY, const float* __restrict__ W,
        const float* __restrict__ dinv, const float* __restrict__ bias,
        double* __restrict__ stats_out, int n) {
    __shared__ double ls[256], lq[256];
    int lane = threadIdx.x & 63;
    float w[64];
    #pragma unroll
    for (int k = 0; k < 64; ++k) w[k] = W[k * 64 + lane];
    float bv = bias[lane];

    int wave  = (blockIdx.x * blockDim.x + threadIdx.x) >> 6;
    int nwave = (gridDim.x * blockDim.x) >> 6;
    double s = 0.0, sq = 0.0;

    for (int i = wave; i < n; i += nwave) {
        int wr = __builtin_amdgcn_readfirstlane(i);
        const float* __restrict__ row = SY + (size_t)wr * 64;
        float a0 = 0.f, a1 = 0.f, a2 = 0.f, a3 = 0.f;
        #pragma unroll
        for (int k = 0; k < 16; ++k) {
            a0 = fmaf(row[k],      w[k],      a0);
            a1 = fmaf(row[k + 16], w[k + 16], a1);
            a2 = fmaf(row[k + 32], w[k + 32], a2);
            a3 = fmaf(row[k + 48], w[k + 48], a3);
        }
        float yv = dinv[wr] * ((a0 + a1) + (a2 + a3)) + bv;
        SY[(size_t)wr * 64 + lane] = yv;
        s += (double)yv; sq += (double)yv * (double)yv;
    }

    ls[threadIdx.x] = s; lq[threadIdx.x] = sq;
    __syncthreads();
    if (threadIdx.x < 64) {
        double ts = ls[threadIdx.x] + ls[threadIdx.x + 64] + ls[threadIdx.x + 128] + ls[threadIdx.x + 192];
        double tq = lq[threadIdx.x] + lq[threadIdx.x + 64] + lq[threadIdx.x + 128] + lq[threadIdx.x + 192];
        atomicAdd(&stats_out[threadIdx.x], ts);
        atomicAdd(&stats_out[64 + threadIdx.x], tq);
    }
}

// ---- head: hs3[row] = (relu(BN(y2[row])) . W3) * dinv[row] ----
__global__ void head_w3(const float* __restrict__ Y, const double* __restrict__ stats,
                        const float* __restrict__ g, const float* __restrict__ bt,
                        const float* __restrict__ W3, const float* __restrict__ dinv,
                        float* __restrict__ hs3, int n) {
    int lane = threadIdx.x & 63;
    double mean = stats[lane] / n;
    double var  = stats[64 + lane] / n - mean * mean;
    float scale = (float)(1.0 / sqrt(var + 1e-5)) * g[lane];
    float shift = bt[lane] - (float)mean * scale;
    float w = W3[lane];
    int wave  = (blockIdx.x * blockDim.x + threadIdx.x) >> 6;
    int nwave = (gridDim.x * blockDim.x) >> 6;
    for (int row = wave; row < n; row += nwave) {
        float v = fmaxf(Y[(size_t)row * 64 + lane] * scale + shift, 0.f) * w;
        #pragma unroll
        for (int o = 32; o > 0; o >>= 1) v += __shfl_down(v, o, 64);
        if (lane == 0) hs3[row] = v * dinv[row];
    }
}

// ---- layer-3 aggregation: wave per node, lane-parallel edge gather ----
__global__ void agg1(const float* __restrict__ hs3, const int* __restrict__ csr,
                     const int* __restrict__ off, const float* __restrict__ dinv,
                     const float* __restrict__ b3, float* __restrict__ out, int n) {
    float b = b3[0];
    int lane  = threadIdx.x & 63;
    int wave  = (blockIdx.x * blockDim.x + threadIdx.x) >> 6;
    int nwave = (gridDim.x * blockDim.x) >> 6;
    for (int i = wave; i < n; i += nwave) {
        int beg = off[i], end = off[i + 1];
        float acc = 0.f;
        for (int e = beg + lane; e < end; e += 64) acc += hs3[csr[e]];
        #pragma unroll
        for (int o = 32; o > 0; o >>= 1) acc += __shfl_down(acc, o, 64);
        if (lane == 0) out[i] = dinv[i] * (acc + hs3[i]) + b;
    }
}

extern "C" void kernel_launch(void* const* d_in, const int* in_sizes, int n_in,
                              void* d_out, int out_size, void* d_ws, size_t ws_size,
                              hipStream_t stream) {
    const float* x   = (const float*)d_in[0];
    const float* W1  = (const float*)d_in[1];
    const float* b1  = (const float*)d_in[2];
    const float* g1  = (const float*)d_in[3];
    const float* bt1 = (const float*)d_in[4];
    const float* W2  = (const float*)d_in[5];
    const float* b2  = (const float*)d_in[6];
    const float* g2  = (const float*)d_in[7];
    const float* bt2 = (const float*)d_in[8];
    const float* W3  = (const float*)d_in[9];
    const float* b3  = (const float*)d_in[10];
    const int*  edge = (const int*)d_in[11];

    int n = in_sizes[0] / 64;
    int E = in_sizes[11] / 2;
    const int* src = edge;
    const int* dst = edge + E;
    float* out = (float*)d_out;
    int nblk = (n + 255) / 256;

    // ---- workspace ----
    char* p = (char*)d_ws;
    double* stats = (double*)p;            p += 256 * sizeof(double);  // L1:0..127, L2:128..255
    float* dinv   = (float*)p;             p += ((n + 63) & ~63) * sizeof(float);
    int* degi     = (int*)p;               p += ((n + 63) & ~63) * sizeof(int);
    int* off      = (int*)p;               p += ((n + 64) & ~63) * sizeof(int);
    int* cur      = (int*)p;               p += ((n + 63) & ~63) * sizeof(int);
    int* part     = (int*)p;               p += 256 * sizeof(int);
    int* csr      = (int*)p;               p += (size_t)E * sizeof(int);
    unsigned* A   = (unsigned*)p;          p += (size_t)n * 32 * sizeof(unsigned); // bf16 T
    float* B      = (float*)p;             p += (size_t)n * 64 * sizeof(float);    // S / Y (in-place)
    float* hs3    = (float*)p;             /* n floats */

    hipMemsetAsync(degi, 0, n * sizeof(int), stream);
    hipMemsetAsync(stats, 0, 256 * sizeof(double), stream);

    // CSR build
    deg_count<<<2048, 256, 0, stream>>>(dst, degi, E);
    scan_part<<<nblk, 256, 0, stream>>>(degi, part, n);
    scan_root<<<1, 256, 0, stream>>>(part, nblk);
    scan_write<<<nblk, 256, 0, stream>>>(degi, part, off, cur, dinv, n);
    csr_fill_x<<<2048, 256, 0, stream>>>(src, dst, cur, csr, E, n);

    // layer 1: T1 = bf16(x*dinv) ; S1 = gather-sum ; Y1 = dinv*S1@W1+b1 (in place)
    prescale<<<1024, 256, 0, stream>>>(x, dinv, A, n);
    agg_s<<<2048, 256, 0, stream>>>((const uint4*)A, csr, off, B, n);
    trans64<<<2048, 256, 0, stream>>>(B, W1, dinv, b1, stats, n);
    // layer 2: T2 = bf16(relu(BN1(Y1))*dinv) ; same pipeline
    bnrelu_scale<<<1024, 256, 0, stream>>>(B, stats, g1, bt1, dinv, A, n);
    agg_s<<<2048, 256, 0, stream>>>((const uint4*)A, csr, off, B, n);
    trans64<<<2048, 256, 0, stream>>>(B, W2, dinv, b2, stats + 128, n);
    // layer 3 (f32 path, tiny)
    head_w3<<<2048, 256, 0, stream>>>(B, stats + 128, g2, bt2, W3, dinv, hs3, n);
    agg1<<<2048, 256, 0, stream>>>(hs3, csr, off, dinv, b3, out, n);
}